// Round 5
// baseline (253.021 us; speedup 1.0000x reference)
//
#include <hip/hip_runtime.h>
#include <hip/hip_bf16.h>

#define B_SZ 4
#define T_SEQ 1024
#define DM 128
#define ED_ 256
#define NS 64

// workspace layout (float elements). Total = 5,341,184 floats = 21.4 MB.
// Aliasing: delta overwrites xsr (xsr dead after k3). No other aliases.
#define OFF_Z      0u         /* 524288  f32  z (residual, read by K6)            */
#define OFF_BM     524288u    /* 262144  f32  B matrix                            */
#define OFF_CM     786432u    /* 262144  f32  C matrix                            */
#define OFF_XSR    1048576u   /* 1048576 f32  conv input; later delta             */
#define OFF_ZG     2097152u   /* 1048576 f32  gate (read by K6)                   */
#define OFF_XS     3145728u   /* 1048576 f32  conv+silu output                    */
#define OFF_WC     4194304u   /* 98304   f32  combined x_proj/dt weight (384x256) */
#define OFF_YR     4292608u   /* 1048576 f32  raw scan output                     */
#define OFF_DELTA  (OFF_XSR)

__device__ __forceinline__ float sigmoidf_(float x){ return 1.f/(1.f+__expf(-x)); }

// One DPP reduce step: p += dpp(p). After 0x111,0x112,0x114,0x118 lane15 of each
// row-of-16 holds the row sum; 0x142 (row_bcast15) and 0x143 (row_bcast31) merge
// rows; lane 63 holds the wave total. Invalid-source lanes contribute 0.
#define DPPSTEP(p, ctl) p += __int_as_float(__builtin_amdgcn_update_dpp(0, __float_as_int(p), ctl, 0xf, 0xf, false))

// K2f: fused [z = zseq + aux@auxW.T + auxb ; zn = RMSNorm(z)*rms_w] staged to LDS,
// then xz = zn @ in_proj_W.T -> xsr (cols 0..255), zg (cols 256..511). 8 rows/block.
__global__ __launch_bounds__(256) void k2_fused(const float* zseq, const float* aux, const float* auxW,
                                                const float* auxb, const float* rmsw, const float* W,
                                                float* z, float* xsr, float* zg){
  __shared__ float at[128][8];
  int bt0 = blockIdx.x*8; int tid = threadIdx.x;
  // ---- fused k1: 8 rows, 32 lanes each, 4 d's per lane ----
  {
    int r = tid>>5, l = tid&31;
    int bt = bt0 + r;
    float a0 = aux[bt*3+0], a1 = aux[bt*3+1], a2 = aux[bt*3+2];
    float zv[4]; float ssq = 0.f;
    #pragma unroll
    for (int j=0;j<4;j++){
      int d = l + 32*j;
      float v = zseq[bt*DM+d] + a0*auxW[d*3+0] + a1*auxW[d*3+1] + a2*auxW[d*3+2] + auxb[d];
      zv[j] = v; ssq += v*v;
    }
    #pragma unroll
    for (int m=16;m>=1;m>>=1) ssq += __shfl_xor(ssq, m);  // reduce within 32-lane group
    float rinv = rsqrtf(ssq*(1.f/DM) + 1e-5f);
    #pragma unroll
    for (int j=0;j<4;j++){
      int d = l + 32*j;
      z[bt*DM+d] = zv[j];
      at[d][r] = zv[j]*rinv*rmsw[d];
    }
  }
  __syncthreads();
  // ---- GEMM: 512 cols, thread owns col tid and tid+256 for 8 rows ----
  float acc0[8], acc1[8];
  #pragma unroll
  for (int r=0;r<8;r++){ acc0[r]=0.f; acc1[r]=0.f; }
  int c0 = tid, c1 = tid+256;
  for (int k=0;k<128;k+=4){
    float4 w0v = *(const float4*)(W + c0*128 + k);
    float4 w1v = *(const float4*)(W + c1*128 + k);
    float w0[4] = {w0v.x, w0v.y, w0v.z, w0v.w};
    float w1[4] = {w1v.x, w1v.y, w1v.z, w1v.w};
    #pragma unroll
    for (int kk=0;kk<4;kk++){
      float a[8];
      *(float4*)&a[0] = *(const float4*)&at[k+kk][0];
      *(float4*)&a[4] = *(const float4*)&at[k+kk][4];
      #pragma unroll
      for (int r=0;r<8;r++){ acc0[r] = fmaf(a[r], w0[kk], acc0[r]); acc1[r] = fmaf(a[r], w1[kk], acc1[r]); }
    }
  }
  #pragma unroll
  for (int r=0;r<8;r++){
    int bt = bt0+r;
    xsr[bt*ED_ + c0] = acc0[r];
    zg [bt*ED_ + c0] = acc1[r];
  }
}

// K3: causal depthwise conv (k=4, left pad 3) + bias + SiLU
__global__ __launch_bounds__(256) void k3_conv(const float* xsr, const float* convW, const float* convb, float* xs){
  int bt = blockIdx.x; int e = threadIdx.x; int t = bt & (T_SEQ-1);
  float4 wv = *(const float4*)(convW + e*4);
  float s = convb[e];
  if (t>=3) s += xsr[(bt-3)*ED_+e]*wv.x;
  if (t>=2) s += xsr[(bt-2)*ED_+e]*wv.y;
  if (t>=1) s += xsr[(bt-1)*ED_+e]*wv.z;
  s += xsr[bt*ED_+e]*wv.w;
  xs[bt*ED_+e] = s * sigmoidf_(s);
}

// K4a: combined weight: rows 0..255 = dt_W @ x_proj_W[:8]; rows 256..383 = x_proj_W[8:136]
__global__ __launch_bounds__(256) void k4a_wc(const float* xprojW, const float* dtW, float* Wc){
  int r = blockIdx.x; int k = threadIdx.x;
  float v;
  if (r < 256){
    v = 0.f;
    #pragma unroll
    for (int j=0;j<8;j++) v += dtW[r*8+j] * xprojW[j*256+k];
  } else {
    v = xprojW[(8 + r-256)*256 + k];
  }
  Wc[r*256+k] = v;
}

// K4b: [delta_pre | B | C] = xs @ Wc.T ; delta = softplus(delta_pre + dt_b)
__global__ __launch_bounds__(384) void k4b_xproj(const float* xs, const float* Wc, const float* dtb,
                                                 float* delta, float* Bm, float* Cm){
  __shared__ float at[256][8];
  int bt0 = blockIdx.x*8; int tid = threadIdx.x;
  for (int i=tid;i<2048;i+=384){ int r=i>>8,k=i&255; at[k][r] = xs[(bt0+r)*ED_ + k]; }
  __syncthreads();
  float acc[8];
  #pragma unroll
  for (int r=0;r<8;r++) acc[r]=0.f;
  int c = tid;
  for (int k=0;k<256;k+=4){
    float4 wv = *(const float4*)(Wc + c*256 + k);
    float w[4] = {wv.x, wv.y, wv.z, wv.w};
    #pragma unroll
    for (int kk=0;kk<4;kk++){
      float a[8];
      *(float4*)&a[0] = *(const float4*)&at[k+kk][0];
      *(float4*)&a[4] = *(const float4*)&at[k+kk][4];
      #pragma unroll
      for (int r=0;r<8;r++) acc[r] = fmaf(a[r], w[kk], acc[r]);
    }
  }
  if (c < 256){
    float bc = dtb[c];
    #pragma unroll
    for (int r=0;r<8;r++){
      float x = acc[r] + bc;
      delta[(bt0+r)*ED_ + c] = (x > 20.f) ? x : log1pf(__expf(x));
    }
  } else if (c < 320){
    #pragma unroll
    for (int r=0;r<8;r++) Bm[(bt0+r)*NS + (c-256)] = acc[r];
  } else {
    #pragma unroll
    for (int r=0;r<8;r++) Cm[(bt0+r)*NS + (c-320)] = acc[r];
  }
}

// K5: SINGLE-PASS scan. One wave per (b,e) — 1024 waves = 1/SIMD on 256 CUs.
// lane = state n. Serial over all T=1024; 8x unroll for load batching + 8
// independent DPP reduce chains per dependency level. Stores raw dot
// p[t] = sum_n h*C from lane 63; gate applied in K6.
__global__ __launch_bounds__(256) void k5_scan(const float* delta, const float* xs, const float* Bm,
                                               const float* Cm, const float* Alog, float* yraw){
  int w = blockIdx.x*4 + (threadIdx.x>>6);
  int n = threadIdx.x & 63;
  int e = w & 255, b = w >> 8;
  float A = -__expf(Alog[e*NS+n]);
  const float* pd = delta + (size_t)(b*T_SEQ)*ED_ + e;
  const float* px = xs    + (size_t)(b*T_SEQ)*ED_ + e;
  const float* pb = Bm    + (size_t)(b*T_SEQ)*NS  + n;
  const float* pc = Cm    + (size_t)(b*T_SEQ)*NS  + n;
  float*       py = yraw  + (size_t)(b*T_SEQ)*ED_ + e;
  float h = 0.f;
  bool last = (n==63);
  for (int t=0; t<T_SEQ; t+=8){
    float dl[8], xx[8], bb[8], cc[8], pp[8];
    #pragma unroll
    for (int j=0;j<8;j++){
      dl[j] = pd[(t+j)*ED_];
      xx[j] = px[(t+j)*ED_];
      bb[j] = pb[(t+j)*NS];
      cc[j] = pc[(t+j)*NS];
    }
    #pragma unroll
    for (int j=0;j<8;j++){
      float a = __expf(dl[j]*A);
      h = fmaf(a, h, dl[j]*xx[j]*bb[j]);
      pp[j] = h*cc[j];
    }
    #pragma unroll
    for (int j=0;j<8;j++) DPPSTEP(pp[j], 0x111);
    #pragma unroll
    for (int j=0;j<8;j++) DPPSTEP(pp[j], 0x112);
    #pragma unroll
    for (int j=0;j<8;j++) DPPSTEP(pp[j], 0x114);
    #pragma unroll
    for (int j=0;j<8;j++) DPPSTEP(pp[j], 0x118);
    #pragma unroll
    for (int j=0;j<8;j++) DPPSTEP(pp[j], 0x142);
    #pragma unroll
    for (int j=0;j<8;j++) DPPSTEP(pp[j], 0x143);
    if (last){
      #pragma unroll
      for (int j=0;j<8;j++) py[(t+j)*ED_] = pp[j];
    }
  }
}

// K6: y = (yraw + D*xs)*silu(zg);  out = LayerNorm(y @ out_proj_W.T + 2*z)*ln_w + ln_b
__global__ __launch_bounds__(256) void k6_out(const float* yraw, const float* xs, const float* zg,
                                               const float* Dp, const float* W, const float* z,
                                               const float* lnw, const float* lnb, float* out){
  __shared__ float yt[256][8];
  __shared__ float psum[4][4], psq[4][4];
  int bt0 = blockIdx.x*8; int tid = threadIdx.x;
  int d = tid & 127, gdx = tid>>7;
  for (int i=tid;i<2048;i+=256){
    int r=i>>8,k=i&255; int bt=bt0+r;
    float zgv = zg[bt*ED_ + k];
    float yv  = yraw[bt*ED_ + k] + Dp[k]*xs[bt*ED_ + k];
    yt[k][r] = yv * zgv * sigmoidf_(zgv);
  }
  __syncthreads();
  float acc[4] = {0.f,0.f,0.f,0.f};
  for (int k=0;k<256;k+=4){
    float4 wv = *(const float4*)(W + d*256 + k);
    float w[4] = {wv.x, wv.y, wv.z, wv.w};
    #pragma unroll
    for (int kk=0;kk<4;kk++){
      float4 q = *(const float4*)&yt[k+kk][gdx*4];
      acc[0] = fmaf(q.x, w[kk], acc[0]);
      acc[1] = fmaf(q.y, w[kk], acc[1]);
      acc[2] = fmaf(q.z, w[kk], acc[2]);
      acc[3] = fmaf(q.w, w[kk], acc[3]);
    }
  }
  float val[4];
  #pragma unroll
  for (int j=0;j<4;j++){
    int bt = bt0 + gdx*4 + j;
    val[j] = acc[j] + 2.f*z[bt*DM + d];
  }
  int w_id = tid>>6;
  #pragma unroll
  for (int j=0;j<4;j++){
    float s = val[j], q = val[j]*val[j];
    #pragma unroll
    for (int off=32; off>=1; off>>=1){ s += __shfl_down(s, off); q += __shfl_down(q, off); }
    if ((tid&63)==0){ psum[w_id][j]=s; psq[w_id][j]=q; }
  }
  __syncthreads();
  float lw = lnw[d], lb = lnb[d];
  #pragma unroll
  for (int j=0;j<4;j++){
    int bt = bt0 + gdx*4 + j;
    float sum = psum[gdx*2][j] + psum[gdx*2+1][j];
    float sq  = psq [gdx*2][j] + psq [gdx*2+1][j];
    float mu  = sum*(1.f/DM);
    float var = sq*(1.f/DM) - mu*mu;
    float inv = rsqrtf(var + 1e-5f);
    out[bt*DM + d] = (val[j]-mu)*inv*lw + lb;
  }
}

extern "C" void kernel_launch(void* const* d_in, const int* in_sizes, int n_in,
                              void* d_out, int out_size, void* d_ws, size_t ws_size,
                              hipStream_t stream){
  const float* zseq = (const float*)d_in[0];
  const float* aux  = (const float*)d_in[1];
  const float* auxW = (const float*)d_in[2];
  const float* auxb = (const float*)d_in[3];
  const float* lnw  = (const float*)d_in[4];
  const float* lnb  = (const float*)d_in[5];
  const float* rmsw = (const float*)d_in[6];
  const float* inW  = (const float*)d_in[7];
  const float* convW= (const float*)d_in[8];
  const float* convb= (const float*)d_in[9];
  const float* xpW  = (const float*)d_in[10];
  const float* dtW  = (const float*)d_in[11];
  const float* dtb  = (const float*)d_in[12];
  const float* Alog = (const float*)d_in[13];
  const float* Dp   = (const float*)d_in[14];
  const float* outW = (const float*)d_in[15];
  float* out = (float*)d_out;
  float* ws = (float*)d_ws;

  float* z   = ws+OFF_Z;
  float* Bm  = ws+OFF_BM;   float* Cm = ws+OFF_CM;
  float* xsr = ws+OFF_XSR;  float* zg = ws+OFF_ZG;   float* xs = ws+OFF_XS;
  float* Wc  = ws+OFF_WC;
  float* dl  = ws+OFF_DELTA;
  float* yr  = ws+OFF_YR;

  k2_fused <<<512,256,0,stream>>>(zseq,aux,auxW,auxb,rmsw,inW,z,xsr,zg);
  k3_conv  <<<4096,256,0,stream>>>(xsr,convW,convb,xs);
  k4a_wc   <<<384,256,0,stream>>>(xpW,dtW,Wc);
  k4b_xproj<<<512,384,0,stream>>>(xs,Wc,dtb,dl,Bm,Cm);
  k5_scan  <<<256,256,0,stream>>>(dl,xs,Bm,Cm,Alog,yr);
  k6_out   <<<512,256,0,stream>>>(yr,xs,zg,Dp,outW,z,lnw,lnb,out);
}

// Round 6
// 232.561 us; speedup vs baseline: 1.0880x; 1.0880x over previous
//
#include <hip/hip_runtime.h>
#include <hip/hip_bf16.h>

#define B_SZ 4
#define T_SEQ 1024
#define DM 128
#define ED_ 256
#define NS 64

// workspace layout (float elements). Total = 6,389,760 floats = 25.6 MB (same as R3's accepted size).
// NOTE: delta NO LONGER aliases xsr — conv (fused in k4b) reads xsr rows bt0-3..bt0+7
// while delta writes happen in the same kernel from other blocks.
#define OFF_Z      0u         /* 524288  f32  z (residual, read by K6)            */
#define OFF_BM     524288u    /* 262144  f32  B matrix                            */
#define OFF_CM     786432u    /* 262144  f32  C matrix                            */
#define OFF_XSR    1048576u   /* 1048576 f32  conv input (k2f -> k4b)             */
#define OFF_ZG     2097152u   /* 1048576 f32  gate (read by K6)                   */
#define OFF_XS     3145728u   /* 1048576 f32  conv+silu output (k4b -> k5,k6)     */
#define OFF_WC     4194304u   /* 98304   f32  combined x_proj/dt weight (384x256) */
#define OFF_YR     4292608u   /* 1048576 f32  raw scan output (k5 -> k6)          */
#define OFF_DELTA  5341184u   /* 1048576 f32  softplus delta (k4b -> k5)          */

__device__ __forceinline__ float sigmoidf_(float x){ return 1.f/(1.f+__expf(-x)); }

// One DPP reduce step: p += dpp(p). 0x111,0x112,0x114,0x118 = row_shr 1/2/4/8
// (per-16 prefix), 0x142/0x143 = row_bcast15/31 (merge rows). Lane 63 = total.
#define DPPSTEP(p, ctl) p += __int_as_float(__builtin_amdgcn_update_dpp(0, __float_as_int(p), ctl, 0xf, 0xf, false))

// K2f: blocks 0..511: fused [z = zseq+aux@auxW.T+auxb ; zn=RMSNorm(z)*rms_w] -> LDS,
//      then xz = zn @ in_proj_W.T -> xsr | zg. 8 rows/block.
//      blocks 512..895: build combined weight Wc (rows 0..255 = dt_W@x_proj_W[:8],
//      rows 256..383 = x_proj_W[8:136]).
__global__ __launch_bounds__(256) void k2_fused(const float* zseq, const float* aux, const float* auxW,
                                                const float* auxb, const float* rmsw, const float* W,
                                                const float* xprojW, const float* dtW,
                                                float* z, float* xsr, float* zg, float* Wc){
  if (blockIdx.x >= 512){
    int r = blockIdx.x - 512; int k = threadIdx.x;
    float v;
    if (r < 256){
      v = 0.f;
      #pragma unroll
      for (int j=0;j<8;j++) v += dtW[r*8+j] * xprojW[j*256+k];
    } else {
      v = xprojW[(8 + r-256)*256 + k];
    }
    Wc[r*256+k] = v;
    return;
  }
  __shared__ float at[128][8];
  int bt0 = blockIdx.x*8; int tid = threadIdx.x;
  {
    int r = tid>>5, l = tid&31;
    int bt = bt0 + r;
    float a0 = aux[bt*3+0], a1 = aux[bt*3+1], a2 = aux[bt*3+2];
    float zv[4]; float ssq = 0.f;
    #pragma unroll
    for (int j=0;j<4;j++){
      int d = l + 32*j;
      float v = zseq[bt*DM+d] + a0*auxW[d*3+0] + a1*auxW[d*3+1] + a2*auxW[d*3+2] + auxb[d];
      zv[j] = v; ssq += v*v;
    }
    #pragma unroll
    for (int m=16;m>=1;m>>=1) ssq += __shfl_xor(ssq, m);
    float rinv = rsqrtf(ssq*(1.f/DM) + 1e-5f);
    #pragma unroll
    for (int j=0;j<4;j++){
      int d = l + 32*j;
      z[bt*DM+d] = zv[j];
      at[d][r] = zv[j]*rinv*rmsw[d];
    }
  }
  __syncthreads();
  float acc0[8], acc1[8];
  #pragma unroll
  for (int r=0;r<8;r++){ acc0[r]=0.f; acc1[r]=0.f; }
  int c0 = tid, c1 = tid+256;
  for (int k=0;k<128;k+=4){
    float4 w0v = *(const float4*)(W + c0*128 + k);
    float4 w1v = *(const float4*)(W + c1*128 + k);
    float w0[4] = {w0v.x, w0v.y, w0v.z, w0v.w};
    float w1[4] = {w1v.x, w1v.y, w1v.z, w1v.w};
    #pragma unroll
    for (int kk=0;kk<4;kk++){
      float a[8];
      *(float4*)&a[0] = *(const float4*)&at[k+kk][0];
      *(float4*)&a[4] = *(const float4*)&at[k+kk][4];
      #pragma unroll
      for (int r=0;r<8;r++){ acc0[r] = fmaf(a[r], w0[kk], acc0[r]); acc1[r] = fmaf(a[r], w1[kk], acc1[r]); }
    }
  }
  #pragma unroll
  for (int r=0;r<8;r++){
    int bt = bt0+r;
    xsr[bt*ED_ + c0] = acc0[r];
    zg [bt*ED_ + c0] = acc1[r];
  }
}

// K4b: staging computes conv(k=4)+bias+SiLU from xsr (writes xs), then
// [delta_pre | B | C] = xs @ Wc.T ; delta = softplus(delta_pre + dt_b)
__global__ __launch_bounds__(384) void k4b_xproj(const float* xsr, const float* convW, const float* convb,
                                                 const float* Wc, const float* dtb,
                                                 float* xs, float* delta, float* Bm, float* Cm){
  __shared__ float at[256][8];
  int bt0 = blockIdx.x*8; int tid = threadIdx.x;
  for (int i=tid;i<2048;i+=384){
    int r=i>>8,k=i&255; int bt=bt0+r; int t = bt & (T_SEQ-1);
    float4 wv = *(const float4*)(convW + k*4);
    float s = convb[k];
    if (t>=3) s += xsr[(bt-3)*ED_+k]*wv.x;
    if (t>=2) s += xsr[(bt-2)*ED_+k]*wv.y;
    if (t>=1) s += xsr[(bt-1)*ED_+k]*wv.z;
    s += xsr[bt*ED_+k]*wv.w;
    float v = s * sigmoidf_(s);
    at[k][r] = v;
    xs[bt*ED_+k] = v;
  }
  __syncthreads();
  float acc[8];
  #pragma unroll
  for (int r=0;r<8;r++) acc[r]=0.f;
  int c = tid;
  for (int k=0;k<256;k+=4){
    float4 wv = *(const float4*)(Wc + c*256 + k);
    float w[4] = {wv.x, wv.y, wv.z, wv.w};
    #pragma unroll
    for (int kk=0;kk<4;kk++){
      float a[8];
      *(float4*)&a[0] = *(const float4*)&at[k+kk][0];
      *(float4*)&a[4] = *(const float4*)&at[k+kk][4];
      #pragma unroll
      for (int r=0;r<8;r++) acc[r] = fmaf(a[r], w[kk], acc[r]);
    }
  }
  if (c < 256){
    float bc = dtb[c];
    #pragma unroll
    for (int r=0;r<8;r++){
      float x = acc[r] + bc;
      delta[(bt0+r)*ED_ + c] = (x > 20.f) ? x : log1pf(__expf(x));
    }
  } else if (c < 320){
    #pragma unroll
    for (int r=0;r<8;r++) Bm[(bt0+r)*NS + (c-256)] = acc[r];
  } else {
    #pragma unroll
    for (int r=0;r<8;r++) Cm[(bt0+r)*NS + (c-320)] = acc[r];
  }
}

// K5: single-pass scan, one wave per (b,e). XCD-aware swizzle: block i -> XCD i%8
// owns e in [32*(i%8), 32*(i%8)+32), so each 64B line of delta/xs (16 e's) is
// touched by exactly one XCD's L2. Register double-buffer: load batch t+8 while
// computing batch t. launch_bounds(256,1) -> VGPRs are free (grid-limited occupancy).
__global__ __launch_bounds__(256,1) void k5_scan(const float* delta, const float* xs, const float* Bm,
                                                  const float* Cm, const float* Alog, float* yraw){
  int i = blockIdx.x;
  int w = threadIdx.x >> 6;
  int n = threadIdx.x & 63;
  int x = i & 7;
  int r = i >> 3;          // 0..31
  int b = r & 3;
  int g = r >> 2;          // 0..7
  int e = x*32 + g*4 + w;
  float A = -__expf(Alog[e*NS+n]);
  const float* pd = delta + (size_t)(b*T_SEQ)*ED_ + e;
  const float* px = xs    + (size_t)(b*T_SEQ)*ED_ + e;
  const float* pb = Bm    + (size_t)(b*T_SEQ)*NS  + n;
  const float* pc = Cm    + (size_t)(b*T_SEQ)*NS  + n;
  float*       py = yraw  + (size_t)(b*T_SEQ)*ED_ + e;
  bool last = (n==63);
  float h = 0.f;

  float dA[8], xA[8], bA[8], cA[8];
  float dB[8], xB[8], bB[8], cB[8];

  #pragma unroll
  for (int j=0;j<8;j++){ dA[j]=pd[j*ED_]; xA[j]=px[j*ED_]; bA[j]=pb[j*NS]; cA[j]=pc[j*NS]; }

  for (int t=0; t<T_SEQ; t+=16){
    // prefetch t+8 into B
    #pragma unroll
    for (int j=0;j<8;j++){ int s=t+8+j; dB[j]=pd[s*ED_]; xB[j]=px[s*ED_]; bB[j]=pb[s*NS]; cB[j]=pc[s*NS]; }
    // compute batch A (t..t+7)
    {
      float a[8], pp[8];
      #pragma unroll
      for (int j=0;j<8;j++) a[j] = __expf(dA[j]*A);
      #pragma unroll
      for (int j=0;j<8;j++){ h = fmaf(a[j], h, dA[j]*xA[j]*bA[j]); pp[j] = h*cA[j]; }
      #pragma unroll
      for (int j=0;j<8;j++) DPPSTEP(pp[j], 0x111);
      #pragma unroll
      for (int j=0;j<8;j++) DPPSTEP(pp[j], 0x112);
      #pragma unroll
      for (int j=0;j<8;j++) DPPSTEP(pp[j], 0x114);
      #pragma unroll
      for (int j=0;j<8;j++) DPPSTEP(pp[j], 0x118);
      #pragma unroll
      for (int j=0;j<8;j++) DPPSTEP(pp[j], 0x142);
      #pragma unroll
      for (int j=0;j<8;j++) DPPSTEP(pp[j], 0x143);
      if (last){
        #pragma unroll
        for (int j=0;j<8;j++) py[(t+j)*ED_] = pp[j];
      }
    }
    // prefetch t+16 into A (guarded: stay inside workspace)
    if (t+16 < T_SEQ){
      #pragma unroll
      for (int j=0;j<8;j++){ int s=t+16+j; dA[j]=pd[s*ED_]; xA[j]=px[s*ED_]; bA[j]=pb[s*NS]; cA[j]=pc[s*NS]; }
    }
    // compute batch B (t+8..t+15)
    {
      float a[8], pp[8];
      #pragma unroll
      for (int j=0;j<8;j++) a[j] = __expf(dB[j]*A);
      #pragma unroll
      for (int j=0;j<8;j++){ h = fmaf(a[j], h, dB[j]*xB[j]*bB[j]); pp[j] = h*cB[j]; }
      #pragma unroll
      for (int j=0;j<8;j++) DPPSTEP(pp[j], 0x111);
      #pragma unroll
      for (int j=0;j<8;j++) DPPSTEP(pp[j], 0x112);
      #pragma unroll
      for (int j=0;j<8;j++) DPPSTEP(pp[j], 0x114);
      #pragma unroll
      for (int j=0;j<8;j++) DPPSTEP(pp[j], 0x118);
      #pragma unroll
      for (int j=0;j<8;j++) DPPSTEP(pp[j], 0x142);
      #pragma unroll
      for (int j=0;j<8;j++) DPPSTEP(pp[j], 0x143);
      if (last){
        #pragma unroll
        for (int j=0;j<8;j++) py[(t+8+j)*ED_] = pp[j];
      }
    }
  }
}

// K6: y = (yraw + D*xs)*silu(zg);  out = LayerNorm(y @ out_proj_W.T + 2*z)*ln_w + ln_b
__global__ __launch_bounds__(256) void k6_out(const float* yraw, const float* xs, const float* zg,
                                               const float* Dp, const float* W, const float* z,
                                               const float* lnw, const float* lnb, float* out){
  __shared__ float yt[256][8];
  __shared__ float psum[4][4], psq[4][4];
  int bt0 = blockIdx.x*8; int tid = threadIdx.x;
  int d = tid & 127, gdx = tid>>7;
  for (int i=tid;i<2048;i+=256){
    int r=i>>8,k=i&255; int bt=bt0+r;
    float zgv = zg[bt*ED_ + k];
    float yv  = yraw[bt*ED_ + k] + Dp[k]*xs[bt*ED_ + k];
    yt[k][r] = yv * zgv * sigmoidf_(zgv);
  }
  __syncthreads();
  float acc[4] = {0.f,0.f,0.f,0.f};
  for (int k=0;k<256;k+=4){
    float4 wv = *(const float4*)(W + d*256 + k);
    float w[4] = {wv.x, wv.y, wv.z, wv.w};
    #pragma unroll
    for (int kk=0;kk<4;kk++){
      float4 q = *(const float4*)&yt[k+kk][gdx*4];
      acc[0] = fmaf(q.x, w[kk], acc[0]);
      acc[1] = fmaf(q.y, w[kk], acc[1]);
      acc[2] = fmaf(q.z, w[kk], acc[2]);
      acc[3] = fmaf(q.w, w[kk], acc[3]);
    }
  }
  float val[4];
  #pragma unroll
  for (int j=0;j<4;j++){
    int bt = bt0 + gdx*4 + j;
    val[j] = acc[j] + 2.f*z[bt*DM + d];
  }
  int w_id = tid>>6;
  #pragma unroll
  for (int j=0;j<4;j++){
    float s = val[j], q = val[j]*val[j];
    #pragma unroll
    for (int off=32; off>=1; off>>=1){ s += __shfl_down(s, off); q += __shfl_down(q, off); }
    if ((tid&63)==0){ psum[w_id][j]=s; psq[w_id][j]=q; }
  }
  __syncthreads();
  float lw = lnw[d], lb = lnb[d];
  #pragma unroll
  for (int j=0;j<4;j++){
    int bt = bt0 + gdx*4 + j;
    float sum = psum[gdx*2][j] + psum[gdx*2+1][j];
    float sq  = psq [gdx*2][j] + psq [gdx*2+1][j];
    float mu  = sum*(1.f/DM);
    float var = sq*(1.f/DM) - mu*mu;
    float inv = rsqrtf(var + 1e-5f);
    out[bt*DM + d] = (val[j]-mu)*inv*lw + lb;
  }
}

extern "C" void kernel_launch(void* const* d_in, const int* in_sizes, int n_in,
                              void* d_out, int out_size, void* d_ws, size_t ws_size,
                              hipStream_t stream){
  const float* zseq = (const float*)d_in[0];
  const float* aux  = (const float*)d_in[1];
  const float* auxW = (const float*)d_in[2];
  const float* auxb = (const float*)d_in[3];
  const float* lnw  = (const float*)d_in[4];
  const float* lnb  = (const float*)d_in[5];
  const float* rmsw = (const float*)d_in[6];
  const float* inW  = (const float*)d_in[7];
  const float* convW= (const float*)d_in[8];
  const float* convb= (const float*)d_in[9];
  const float* xpW  = (const float*)d_in[10];
  const float* dtW  = (const float*)d_in[11];
  const float* dtb  = (const float*)d_in[12];
  const float* Alog = (const float*)d_in[13];
  const float* Dp   = (const float*)d_in[14];
  const float* outW = (const float*)d_in[15];
  float* out = (float*)d_out;
  float* ws = (float*)d_ws;

  float* z   = ws+OFF_Z;
  float* Bm  = ws+OFF_BM;   float* Cm = ws+OFF_CM;
  float* xsr = ws+OFF_XSR;  float* zg = ws+OFF_ZG;   float* xs = ws+OFF_XS;
  float* Wc  = ws+OFF_WC;
  float* yr  = ws+OFF_YR;   float* dl = ws+OFF_DELTA;

  k2_fused <<<896,256,0,stream>>>(zseq,aux,auxW,auxb,rmsw,inW,xpW,dtW,z,xsr,zg,Wc);
  k4b_xproj<<<512,384,0,stream>>>(xsr,convW,convb,Wc,dtb,xs,dl,Bm,Cm);
  k5_scan  <<<256,256,0,stream>>>(dl,xs,Bm,Cm,Alog,yr);
  k6_out   <<<512,256,0,stream>>>(yr,xs,zg,Dp,outW,z,lnw,lnb,out);
}